// Round 1
// baseline (45.567 us; speedup 1.0000x reference)
//
#include <hip/hip_runtime.h>
#include <hip/hip_bf16.h>
#include <math.h>

#define HIDDEN 2048
#define NEXP   64
#define NTOK   16384
#define NTGF   512

typedef __attribute__((ext_vector_type(8))) _Float16 f16x8;  // 8 f16 = 4 VGPR (MFMA A/B frag)
typedef __attribute__((ext_vector_type(4))) float   f32x4;   // MFMA C/D frag

// 2-way fp16 RNE split: x = h + l + O(2^-22). Residual exact (Sterbenz), l may be subnormal (ok).
__device__ __forceinline__ void split2_f16(float4 f0, float4 f1, f16x8& h, f16x8& l) {
    float e[8] = {f0.x, f0.y, f0.z, f0.w, f1.x, f1.y, f1.z, f1.w};
    f16x8 hv, lv;
#pragma unroll
    for (int i = 0; i < 8; ++i) {
        _Float16 hh = (_Float16)e[i];        // v_cvt_f16_f32 (RNE)
        float r = e[i] - (float)hh;          // exact residual
        hv[i] = hh;
        lv[i] = (_Float16)r;
    }
    h = hv; l = lv;
}

// ---------------- Kernel 0: w [64][2048] fp32 -> wh/wl f16x8 slots, pre-swizzled ----------------
// Slot (c, e, kgp) holds w[e][c*64 + (kgp^(e&7))*8 .. +7]; flat = c*512 + e*8 + kgp.
// Linear LDS image for global_load_lds; XOR keeps B ds_read_b128 at 2-way (free).
__global__ __launch_bounds__(256) void prep_kernel(
    const float* __restrict__ gw, uint4* __restrict__ wh, uint4* __restrict__ wl)
{
    const int gid = blockIdx.x * 256 + threadIdx.x;   // 0..16383
    const int c   = gid >> 9;
    const int e   = (gid >> 3) & 63;
    const int kgp = gid & 7;
    const int kg  = kgp ^ (e & 7);
    const float* src = gw + (size_t)e * HIDDEN + c * 64 + kg * 8;
    float4 s0 = *(const float4*)src;
    float4 s1 = *(const float4*)(src + 4);
    f16x8 h, l;
    split2_f16(s0, s1, h, l);
    wh[gid] = __builtin_bit_cast(uint4, h);
    wl[gid] = __builtin_bit_cast(uint4, l);
}

// ---------------- Kernel A: split-K MFMA GEMM, fp16 2-way split (hh + hl + lh) ----------------
// grid (NTOK/64, KS) = (256, 4) -> 1024 blocks, 4 blocks/CU (16 waves/CU) for latency cover.
// Wave: 16 tokens (1 m-rep) x 64 experts. Per ks-step: 8 ds_read_b128 feed 12 MFMAs.
// Double-buffer: stage chunk c+1 during compute of chunk c; one barrier per 64-k chunk.
#define STAGE(cg, bo)                                                                     \
    _Pragma("unroll")                                                                     \
    for (int rr = 0; rr < 2; ++rr) {                                                      \
        const int s = rr * 256 + tid;                                                     \
        __builtin_amdgcn_global_load_lds(                                                 \
            (const __attribute__((address_space(1))) void*)(wh + (size_t)(cg) * 512 + s), \
            (__attribute__((address_space(3))) void*)&Bs[(bo) + s], 16, 0, 0);            \
        __builtin_amdgcn_global_load_lds(                                                 \
            (const __attribute__((address_space(1))) void*)(wl + (size_t)(cg) * 512 + s), \
            (__attribute__((address_space(3))) void*)&Bs[(bo) + 512 + s], 16, 0, 0);      \
    }

__global__ __launch_bounds__(256, 4) void gemm_kernel(
    const float* __restrict__ x,     // [NTOK, HIDDEN]
    const uint4* __restrict__ wh,    // [32][64][8] slots (f16 high plane)
    const uint4* __restrict__ wl,    // f16 low plane
    float* __restrict__ part,        // [KS][NTOK][64]
    int klen)                        // HIDDEN / KS
{
    __shared__ uint4 Bs[2 * 1024];   // 2 bufs x (h|l x 512 slots) = 32 KB

    const int tid = threadIdx.x;
    const int l   = tid & 63;
    const int wv  = tid >> 6;
    const int kg  = blockIdx.y;
    const int kbase = kg * klen;
    const int nch   = klen >> 6;     // 64-k chunks
    const int cg0   = kbase >> 6;
    const int t0    = blockIdx.x * 64 + wv * 16;

    // A: lane l -> row t0+(l&15); k-group (l>>4)*8 within each 32-k step
    const float4* xp = (const float4*)(x + (size_t)(t0 + (l & 15)) * HIDDEN + kbase) + ((l >> 4) * 2);

    // B slot base: e=(l&15)+16eg, kgp=((ks<<2)|(l>>4))^(l&7); ks XOR'd at use
    const int lb = ((l & 15) << 3) | ((l >> 4) ^ (l & 7));

    f32x4 acc1[4], acc2[4];          // [eg]
#pragma unroll
    for (int eg = 0; eg < 4; ++eg) {
        acc1[eg] = (f32x4){0.f, 0.f, 0.f, 0.f};
        acc2[eg] = (f32x4){0.f, 0.f, 0.f, 0.f};
    }

    // prologue: stage chunk 0 -> buf 0; load chunk 0's A
    STAGE(cg0, 0)
    float4 a0 = xp[0], a1 = xp[1], a2 = xp[8], a3 = xp[9];
    __syncthreads();

    for (int c = 0; c < nch; ++c) {
        const int buf = c & 1;
        float4 n0 = a0, n1 = a1, n2 = a2, n3 = a3;
        if (c + 1 < nch) {
            STAGE(cg0 + c + 1, (buf ^ 1) * 1024)
            const int fb = (c + 1) * 16;
            n0 = xp[fb + 0]; n1 = xp[fb + 1]; n2 = xp[fb + 8]; n3 = xp[fb + 9];
        }

#pragma unroll
        for (int ks = 0; ks < 2; ++ks) {
            f16x8 ah, al;
            split2_f16(ks ? a2 : a0, ks ? a3 : a1, ah, al);
            const int ib = buf * 1024 + (lb ^ (ks << 2));
#pragma unroll
            for (int eg = 0; eg < 4; ++eg) {
                f16x8 bh = __builtin_bit_cast(f16x8, Bs[ib + eg * 128]);
                f16x8 bl = __builtin_bit_cast(f16x8, Bs[ib + 512 + eg * 128]);
                acc1[eg] = __builtin_amdgcn_mfma_f32_16x16x32_f16(ah, bh, acc1[eg], 0, 0, 0); // hh
                acc2[eg] = __builtin_amdgcn_mfma_f32_16x16x32_f16(ah, bl, acc2[eg], 0, 0, 0); // hl
                acc2[eg] = __builtin_amdgcn_mfma_f32_16x16x32_f16(al, bh, acc2[eg], 0, 0, 0); // lh
            }
        }
        a0 = n0; a1 = n1; a2 = n2; a3 = n3;
        __syncthreads();
    }

    // store: reg (eg,i) -> token t0 + (l>>4)*4 + i, expert eg*16 + (l&15)
    float* pp = part + ((size_t)kg * NTOK + t0) * NEXP;
#pragma unroll
    for (int eg = 0; eg < 4; ++eg)
#pragma unroll
        for (int i = 0; i < 4; ++i)
            pp[(size_t)((l >> 4) * 4 + i) * NEXP + eg * 16 + (l & 15)] =
                acc1[eg][i] + acc2[eg][i];
}

// ---------------- Kernel B: reduce partials + bias + top-2 + weights + mask ----------------
// 512 blocks x 32 tokens (2 blocks/CU, 8 waves/CU) for latency cover on partial reads.
__global__ __launch_bounds__(256) void finish_kernel(
    const float* __restrict__ part,   // [KS][NTOK][64]
    const float* __restrict__ bias_g,
    float* __restrict__ logits,
    float* __restrict__ weights,
    float* __restrict__ idxf,
    float* __restrict__ mask,
    int KS)
{
    __shared__ float Ls[32][65];
    __shared__ int selA[32], selB[32];

    const int tid = threadIdx.x;
    const int bm0 = blockIdx.x * 32;
    const int tn  = tid & 15;        // expert group of 4
    const int tm  = tid >> 4;        // 16 row-groups; each owns rows tm and tm+16

    float4 acc[2];
#pragma unroll
    for (int i = 0; i < 2; ++i) acc[i] = make_float4(0.f, 0.f, 0.f, 0.f);

    for (int kg = 0; kg < KS; ++kg) {
        const float* pb = part + ((size_t)kg * NTOK + bm0) * NEXP;
#pragma unroll
        for (int i = 0; i < 2; ++i) {
            float4 v = *(const float4*)&pb[(tm + 16 * i) * NEXP + 4 * tn];
            acc[i].x += v.x; acc[i].y += v.y; acc[i].z += v.z; acc[i].w += v.w;
        }
    }

    const float4 bv = *(const float4*)&bias_g[4 * tn];
#pragma unroll
    for (int i = 0; i < 2; ++i) {
        const int m = tm + 16 * i;
        float4 v;
        v.x = acc[i].x + bv.x;
        v.y = acc[i].y + bv.y;
        v.z = acc[i].z + bv.z;
        v.w = acc[i].w + bv.w;
        *(float4*)&logits[(size_t)(bm0 + m) * NEXP + 4 * tn] = v;
        Ls[m][4 * tn + 0] = v.x;
        Ls[m][4 * tn + 1] = v.y;
        Ls[m][4 * tn + 2] = v.z;
        Ls[m][4 * tn + 3] = v.w;
    }
    __syncthreads();

    if (tid < 32) {
        const int t = tid;
        float best = -1e30f, second = -1e30f;
        int bi = 0, si = 0;
#pragma unroll
        for (int e = 0; e < NEXP; ++e) {
            float v = Ls[t][e];
            if (v > best)        { second = best; si = bi; best = v; bi = e; }
            else if (v > second) { second = v; si = e; }
        }
        float r  = __expf(second - best);   // softmax denom cancels in the ratio
        float w0 = 1.f / (1.f + r);
        float w1 = r / (1.f + r);
        const int tgl = bm0 + t;
        weights[2 * tgl + 0] = w0;
        weights[2 * tgl + 1] = w1;
        idxf[2 * tgl + 0] = (float)bi;
        idxf[2 * tgl + 1] = (float)si;
        selA[t] = bi;
        selB[t] = si;
    }
    __syncthreads();

    // mask: 64 experts x 2 k x 32 tokens; thread -> 4 (e,k) pairs x 4 tokens (float4)
    const int t8 = tid & 7;          // token group of 4 (8 groups = 32 tokens)
    const int pg = tid >> 3;         // 0..31, 4 pairs each
    const int b0 = 4 * t8;
    int sA0 = selA[b0+0], sA1 = selA[b0+1], sA2 = selA[b0+2], sA3 = selA[b0+3];
    int sB0 = selB[b0+0], sB1 = selB[b0+1], sB2 = selB[b0+2], sB3 = selB[b0+3];
#pragma unroll
    for (int p = 0; p < 4; ++p) {
        const int pair = pg * 4 + p;
        const int e = pair >> 1;
        const int k = pair & 1;
        const int a0 = k ? sB0 : sA0, a1 = k ? sB1 : sA1, a2 = k ? sB2 : sA2, a3 = k ? sB3 : sA3;
        float4 v;
        v.x = (a0 == e) ? 1.f : 0.f;
        v.y = (a1 == e) ? 1.f : 0.f;
        v.z = (a2 == e) ? 1.f : 0.f;
        v.w = (a3 == e) ? 1.f : 0.f;
        *(float4*)&mask[((size_t)e * 2 + k) * NTOK + bm0 + b0] = v;
    }
}

extern "C" void kernel_launch(void* const* d_in, const int* in_sizes, int n_in,
                              void* d_out, int out_size, void* d_ws, size_t ws_size,
                              hipStream_t stream) {
    const float* x  = (const float*)d_in[0];   // [16384, 2048]
    const float* gw = (const float*)d_in[1];   // [64, 2048]
    const float* gb = (const float*)d_in[2];   // [64]

    float* out     = (float*)d_out;
    float* logits  = out;                                  // 1048576
    float* weights = out + (size_t)NTOK * NEXP;            // 32768
    float* idxf    = weights + (size_t)NTOK * 2;           // 32768
    float* mask    = idxf + (size_t)NTOK * 2;              // 2097152

    // ws layout: wh | wl (256 KB each) | partials (KS x 4 MB)
    uint4* wh = (uint4*)d_ws;
    uint4* wl = wh + 16384;
    const size_t hdrB   = 2 * 16384 * sizeof(uint4);               // 512 KB
    const size_t sliceB = (size_t)NTOK * NEXP * sizeof(float);     // 4 MB
    int KS;
    float* part;
    if      (ws_size >= hdrB + 4 * sliceB) { KS = 4; part = (float*)((char*)d_ws + hdrB); }
    else if (ws_size >= hdrB + 2 * sliceB) { KS = 2; part = (float*)((char*)d_ws + hdrB); }
    else                                   { KS = 1; part = logits; }

    const int klen = HIDDEN / KS;
    prep_kernel<<<64, 256, 0, stream>>>(gw, wh, wl);
    dim3 gridA(NTOK / 64, KS);
    gemm_kernel<<<gridA, 256, 0, stream>>>(x, wh, wl, part, klen);
    finish_kernel<<<NTGF, 256, 0, stream>>>(part, gb, logits, weights, idxf, mask, KS);
}